// Round 9
// baseline (76.742 us; speedup 1.0000x reference)
//
#include <hip/hip_runtime.h>
#include <hip/hip_cooperative_groups.h>

namespace cg = cooperative_groups;

// Masked scatter-add: out[index[i]] += rate[i] where starttime[i] <= t < endtime[i].
//
// R1: direct global atomics -> 250-way memory-side contention, 113 us.
// R2: LDS hist + partials + parallel reduce: 45 us.
// R3: plain-store reduce (8 workgroups) latency-bound at 118 us.
// R4: parallel reduce restored -> 36.5 us.
// R5: occupancy 18%->72%: no change. TLP not the constraint.
// R6: batched-ILP: no change. R7: branch-free loads: no change. The 160 MB
//     stream runs at ~5.6 TB/s (~89% of the 6.29 TB/s copy ceiling).
// R8: memset folded + npart=256 -> 31.5 us. Remaining slack = reduce dispatch.
// R9: single cooperative kernel: stream -> flush -> grid.sync() -> grid-
//     parallel reduce (block b owns bins [8b,8b+8), plain stores, no zeroing).
//     256 blocks x 1024 thr = 1 block/CU; worst-case 2/CU packing still fits
//     (32 waves, 16 KB LDS) -> co-residency guaranteed, no deadlock.

#define MAX_BINS 2048   // problem SIZE = 2000; static LDS must be compile-time
#define HIST_BLOCK 1024
#define NPART 256       // partial rows == grid size
#define BPB 8           // bins per block in reduce phase (NPART*BPB >= MAX_BINS)

__global__ void __launch_bounds__(HIST_BLOCK)
fused_hist_reduce_kernel(const int* __restrict__ index,
                         const float* __restrict__ rate,
                         const float* __restrict__ starttime,
                         const float* __restrict__ endtime,
                         const float* __restrict__ t_ptr,
                         float* __restrict__ ws,   // [NPART][size] partials
                         float* __restrict__ out,
                         int n, int size)
{
    __shared__ float hist[MAX_BINS];
    for (int j = threadIdx.x; j < size; j += blockDim.x) hist[j] = 0.0f;
    __syncthreads();

    const float t = t_ptr[0];
    const int tid      = blockIdx.x * blockDim.x + threadIdx.x;
    const int nthreads = gridDim.x * blockDim.x;
    const int nvec     = n >> 2;

    const int4*   idx4v = reinterpret_cast<const int4*>(index);
    const float4* rat4v = reinterpret_cast<const float4*>(rate);
    const float4* st4v  = reinterpret_cast<const float4*>(starttime);
    const float4* en4v  = reinterpret_cast<const float4*>(endtime);

    int i = tid;

    // 2 points/iter, all 8 loads unconditional and independent -> back-to-back
    // issue, single vmcnt drain, no data-dependent branches in the load path.
    for (; i + nthreads < nvec; i += 2 * nthreads) {
        const int ib = i + nthreads;

        const float4 sA = st4v[i];  const float4 eA = en4v[i];
        const int4   iA = idx4v[i]; const float4 rA = rat4v[i];
        const float4 sB = st4v[ib];  const float4 eB = en4v[ib];
        const int4   iB = idx4v[ib]; const float4 rB = rat4v[ib];

        if ((sA.x <= t) & (t < eA.x)) atomicAdd(&hist[iA.x], rA.x);  // ds_add_f32
        if ((sA.y <= t) & (t < eA.y)) atomicAdd(&hist[iA.y], rA.y);
        if ((sA.z <= t) & (t < eA.z)) atomicAdd(&hist[iA.z], rA.z);
        if ((sA.w <= t) & (t < eA.w)) atomicAdd(&hist[iA.w], rA.w);

        if ((sB.x <= t) & (t < eB.x)) atomicAdd(&hist[iB.x], rB.x);
        if ((sB.y <= t) & (t < eB.y)) atomicAdd(&hist[iB.y], rB.y);
        if ((sB.z <= t) & (t < eB.z)) atomicAdd(&hist[iB.z], rB.z);
        if ((sB.w <= t) & (t < eB.w)) atomicAdd(&hist[iB.w], rB.w);
    }

    // Remainder chunk-point (at most one stride left).
    for (; i < nvec; i += nthreads) {
        const float4 s4 = st4v[i];  const float4 e4 = en4v[i];
        const int4   i4 = idx4v[i]; const float4 r4 = rat4v[i];
        if ((s4.x <= t) & (t < e4.x)) atomicAdd(&hist[i4.x], r4.x);
        if ((s4.y <= t) & (t < e4.y)) atomicAdd(&hist[i4.y], r4.y);
        if ((s4.z <= t) & (t < e4.z)) atomicAdd(&hist[i4.z], r4.z);
        if ((s4.w <= t) & (t < e4.w)) atomicAdd(&hist[i4.w], r4.w);
    }

    // Element tail (N % 4) — N=10M divisible by 4, but stay generic.
    for (int k = (nvec << 2) + tid; k < n; k += nthreads) {
        if (starttime[k] <= t && t < endtime[k]) atomicAdd(&hist[index[k]], rate[k]);
    }

    __syncthreads();

    // Coalesced, vectorized flush of this block's private partial row.
    {
        float* part = ws + (size_t)blockIdx.x * size;
        const int nq = size >> 2;
        float4* part4 = reinterpret_cast<float4*>(part);
        const float4* hist4 = reinterpret_cast<const float4*>(hist);
        for (int j = threadIdx.x; j < nq; j += blockDim.x) part4[j] = hist4[j];
        for (int j = (nq << 2) + threadIdx.x; j < size; j += blockDim.x) part[j] = hist[j];
    }

    // ---- grid-wide barrier: all partial rows visible ----
    cg::this_grid().sync();

    // Reduce phase: block b owns bins [b*BPB, b*BPB+BPB). Thread t: bin-lane
    // jj = t&7, partial-group h = t>>3 (128 groups), strided sum over p, then
    // wave shfl tree across h, final cross-wave sum via LDS. Plain stores ->
    // no out-zeroing anywhere.
    const int j0 = blockIdx.x * BPB;
    if (j0 < size) {
        const int t2 = threadIdx.x;
        const int jj = t2 & (BPB - 1);
        const int h  = t2 >> 3;              // 0..127
        const int j  = j0 + jj;

        float s = 0.0f;
        if (j < size) {
            for (int p = h; p < NPART; p += (HIST_BLOCK >> 3))   // 2 iterations
                s += ws[(size_t)p * size + j];
        }
        // Lanes with equal jj within a wave differ by 8,16,32 -> shfl tree.
        s += __shfl_down(s, 32);
        s += __shfl_down(s, 16);
        s += __shfl_down(s, 8);

        // Lanes 0..7 of each wave hold per-(wave, jj) partials. Reuse hist LDS.
        if ((t2 & 63) < BPB) hist[(t2 >> 6) * BPB + jj] = s;
        __syncthreads();
        if (t2 < BPB) {
            float tot = 0.0f;
            #pragma unroll
            for (int w = 0; w < (HIST_BLOCK / 64); ++w) tot += hist[w * BPB + t2];
            const int j2 = j0 + t2;
            if (j2 < size) out[j2] = tot;
        }
    }
}

// ---------- fallback path (ws too small / size too large) ----------

__global__ void __launch_bounds__(256)
reduce_partials_kernel(const float* __restrict__ ws,
                       float* __restrict__ out,
                       int npart, int size)
{
    const int j = blockIdx.x * blockDim.x + threadIdx.x;
    if (j >= size) return;
    const int chunk  = npart / gridDim.y;
    const int bstart = blockIdx.y * chunk;
    const int bend   = (blockIdx.y == gridDim.y - 1) ? npart : bstart + chunk;
    float sum = 0.0f;
    for (int b = bstart; b < bend; ++b) sum += ws[(size_t)b * size + j];
    atomicAdd(&out[j], sum);
}

__global__ void __launch_bounds__(256)
direct_atomic_kernel(const int* __restrict__ index,
                     const float* __restrict__ rate,
                     const float* __restrict__ starttime,
                     const float* __restrict__ endtime,
                     const float* __restrict__ t_ptr,
                     float* __restrict__ out, int n)
{
    const float t = t_ptr[0];
    const int tid      = blockIdx.x * blockDim.x + threadIdx.x;
    const int nthreads = gridDim.x * blockDim.x;
    for (int i = tid; i < n; i += nthreads) {
        if (starttime[i] <= t && t < endtime[i]) atomicAdd(&out[index[i]], rate[i]);
    }
}

extern "C" void kernel_launch(void* const* d_in, const int* in_sizes, int n_in,
                              void* d_out, int out_size, void* d_ws, size_t ws_size,
                              hipStream_t stream)
{
    const int*   index     = (const int*)  d_in[0];
    const float* rate      = (const float*)d_in[1];
    const float* starttime = (const float*)d_in[2];
    const float* endtime   = (const float*)d_in[3];
    const float* t_ptr     = (const float*)d_in[4];

    float* out = (float*)d_out;
    float* ws  = (float*)d_ws;
    int n    = in_sizes[0];
    int size = out_size;

    const bool fused_ok = (size <= MAX_BINS) && (size <= NPART * BPB) &&
                          (ws_size >= (size_t)NPART * (size_t)size * sizeof(float));

    if (fused_ok) {
        void* args[] = { (void*)&index, (void*)&rate, (void*)&starttime,
                         (void*)&endtime, (void*)&t_ptr, (void*)&ws,
                         (void*)&out, (void*)&n, (void*)&size };
        hipLaunchCooperativeKernel((void*)fused_hist_reduce_kernel,
                                   dim3(NPART), dim3(HIST_BLOCK),
                                   args, 0, stream);
    } else {
        hipMemsetAsync(out, 0, (size_t)size * sizeof(float), stream);
        int grid = (n + 255) / 256;
        if (grid > 2048) grid = 2048;
        direct_atomic_kernel<<<grid, 256, 0, stream>>>(
            index, rate, starttime, endtime, t_ptr, out, n);
    }
}

// Round 10
// 31.431 us; speedup vs baseline: 2.4416x; 2.4416x over previous
//
#include <hip/hip_runtime.h>

// Masked scatter-add: out[index[i]] += rate[i] where starttime[i] <= t < endtime[i].
//
// R1: direct global atomics -> 250-way memory-side contention, 113 us.
// R2: LDS hist + partials + parallel reduce: 45 us.
// R3: plain-store reduce (8 workgroups) latency-bound at 118 us.
// R4: parallel reduce restored -> 36.5 us.
// R5: occupancy 18%->72%: no change. TLP not the constraint.
// R6: batched-ILP: no change. R7: branch-free loads: no change. The 160 MB
//     stream runs at ~5.6 TB/s (~89% of the 6.29 TB/s copy ceiling).
// R8: memset folded into hist + npart=256 -> 31.5 us (best).
// R9: cooperative grid.sync() fusion REGRESSED to 76.7 us (grid barrier costs
//     ~25-45 us vs the ~2 us dispatch gap it replaces; stream BW also fell).
// R10: revert to R8. 31.5 us vs ~29-30 us structural floor -> roofline.

#define MAX_BINS 2048   // problem SIZE = 2000; static LDS must be compile-time
#define HIST_BLOCK 1024

__global__ void __launch_bounds__(HIST_BLOCK)
hist_partial_kernel(const int* __restrict__ index,
                    const float* __restrict__ rate,
                    const float* __restrict__ starttime,
                    const float* __restrict__ endtime,
                    const float* __restrict__ t_ptr,
                    float* __restrict__ ws,   // [gridDim.x][size] partials
                    float* __restrict__ out,  // zeroed here (block 0) for the reduce
                    int n, int size)
{
    __shared__ float hist[MAX_BINS];
    for (int j = threadIdx.x; j < size; j += blockDim.x) hist[j] = 0.0f;

    // Fold the d_out memset into this kernel: reduce_partials runs after us in
    // stream order, so zeroing here is race-free. Saves one dispatch.
    if (blockIdx.x == 0) {
        for (int j = threadIdx.x; j < size; j += blockDim.x) out[j] = 0.0f;
    }
    __syncthreads();

    const float t = t_ptr[0];
    const int tid      = blockIdx.x * blockDim.x + threadIdx.x;
    const int nthreads = gridDim.x * blockDim.x;
    const int nvec     = n >> 2;

    const int4*   idx4v = reinterpret_cast<const int4*>(index);
    const float4* rat4v = reinterpret_cast<const float4*>(rate);
    const float4* st4v  = reinterpret_cast<const float4*>(starttime);
    const float4* en4v  = reinterpret_cast<const float4*>(endtime);

    int i = tid;

    // 2 points/iter, all 8 loads unconditional and independent -> back-to-back
    // issue, single vmcnt drain, no data-dependent branches in the load path.
    for (; i + nthreads < nvec; i += 2 * nthreads) {
        const int ib = i + nthreads;

        const float4 sA = st4v[i];  const float4 eA = en4v[i];
        const int4   iA = idx4v[i]; const float4 rA = rat4v[i];
        const float4 sB = st4v[ib];  const float4 eB = en4v[ib];
        const int4   iB = idx4v[ib]; const float4 rB = rat4v[ib];

        if ((sA.x <= t) & (t < eA.x)) atomicAdd(&hist[iA.x], rA.x);  // ds_add_f32
        if ((sA.y <= t) & (t < eA.y)) atomicAdd(&hist[iA.y], rA.y);
        if ((sA.z <= t) & (t < eA.z)) atomicAdd(&hist[iA.z], rA.z);
        if ((sA.w <= t) & (t < eA.w)) atomicAdd(&hist[iA.w], rA.w);

        if ((sB.x <= t) & (t < eB.x)) atomicAdd(&hist[iB.x], rB.x);
        if ((sB.y <= t) & (t < eB.y)) atomicAdd(&hist[iB.y], rB.y);
        if ((sB.z <= t) & (t < eB.z)) atomicAdd(&hist[iB.z], rB.z);
        if ((sB.w <= t) & (t < eB.w)) atomicAdd(&hist[iB.w], rB.w);
    }

    // Remainder chunk-point (at most one stride left).
    for (; i < nvec; i += nthreads) {
        const float4 s4 = st4v[i];  const float4 e4 = en4v[i];
        const int4   i4 = idx4v[i]; const float4 r4 = rat4v[i];
        if ((s4.x <= t) & (t < e4.x)) atomicAdd(&hist[i4.x], r4.x);
        if ((s4.y <= t) & (t < e4.y)) atomicAdd(&hist[i4.y], r4.y);
        if ((s4.z <= t) & (t < e4.z)) atomicAdd(&hist[i4.z], r4.z);
        if ((s4.w <= t) & (t < e4.w)) atomicAdd(&hist[i4.w], r4.w);
    }

    // Element tail (N % 4) — N=10M divisible by 4, but stay generic.
    for (int k = (nvec << 2) + tid; k < n; k += nthreads) {
        if (starttime[k] <= t && t < endtime[k]) atomicAdd(&hist[index[k]], rate[k]);
    }

    __syncthreads();

    // Coalesced, vectorized flush of this block's private partial row.
    float* part = ws + (size_t)blockIdx.x * size;
    const int nq = size >> 2;
    float4* part4 = reinterpret_cast<float4*>(part);
    const float4* hist4 = reinterpret_cast<const float4*>(hist);
    for (int j = threadIdx.x; j < nq; j += blockDim.x) part4[j] = hist4[j];
    for (int j = (nq << 2) + threadIdx.x; j < size; j += blockDim.x) part[j] = hist[j];
}

// Parallel over partials: block (x=j-tile, y=b-chunk). Each thread sums its
// chunk (coalesced: lanes read consecutive j at fixed b) then ONE atomicAdd.
// gridDim.y-way contention per bin -- negligible.
__global__ void __launch_bounds__(256)
reduce_partials_kernel(const float* __restrict__ ws,
                       float* __restrict__ out,
                       int npart, int size)
{
    const int j = blockIdx.x * blockDim.x + threadIdx.x;
    if (j >= size) return;

    const int chunk  = npart / gridDim.y;
    const int bstart = blockIdx.y * chunk;
    const int bend   = (blockIdx.y == gridDim.y - 1) ? npart : bstart + chunk;

    float sum = 0.0f;
    int b = bstart;
    #pragma unroll 8
    for (; b + 8 <= bend; b += 8) {
        sum += ws[(size_t)(b + 0) * size + j];
        sum += ws[(size_t)(b + 1) * size + j];
        sum += ws[(size_t)(b + 2) * size + j];
        sum += ws[(size_t)(b + 3) * size + j];
        sum += ws[(size_t)(b + 4) * size + j];
        sum += ws[(size_t)(b + 5) * size + j];
        sum += ws[(size_t)(b + 6) * size + j];
        sum += ws[(size_t)(b + 7) * size + j];
    }
    for (; b < bend; ++b) sum += ws[(size_t)b * size + j];

    atomicAdd(&out[j], sum);
}

// Fallback (ws too small / size too large): direct predicated global atomics.
__global__ void __launch_bounds__(256)
direct_atomic_kernel(const int* __restrict__ index,
                     const float* __restrict__ rate,
                     const float* __restrict__ starttime,
                     const float* __restrict__ endtime,
                     const float* __restrict__ t_ptr,
                     float* __restrict__ out, int n)
{
    const float t = t_ptr[0];
    const int tid      = blockIdx.x * blockDim.x + threadIdx.x;
    const int nthreads = gridDim.x * blockDim.x;
    for (int i = tid; i < n; i += nthreads) {
        if (starttime[i] <= t && t < endtime[i]) atomicAdd(&out[index[i]], rate[i]);
    }
}

extern "C" void kernel_launch(void* const* d_in, const int* in_sizes, int n_in,
                              void* d_out, int out_size, void* d_ws, size_t ws_size,
                              hipStream_t stream)
{
    const int*   index     = (const int*)  d_in[0];
    const float* rate      = (const float*)d_in[1];
    const float* starttime = (const float*)d_in[2];
    const float* endtime   = (const float*)d_in[3];
    const float* t_ptr     = (const float*)d_in[4];

    float* out = (float*)d_out;
    float* ws  = (float*)d_ws;
    const int n    = in_sizes[0];
    const int size = out_size;

    // npart=256: 1 block/CU (16 waves/CU -- R4/R5 showed >=8 waves/CU is
    // BW-equivalent), partial RT down to 4 MB total.
    int npart = (int)(ws_size / ((size_t)size * sizeof(float)));
    if (npart > 256) npart = 256;

    if (size <= MAX_BINS && npart >= 64) {
        hist_partial_kernel<<<npart, HIST_BLOCK, 0, stream>>>(
            index, rate, starttime, endtime, t_ptr, ws, out, n, size);

        dim3 g2((size + 255) / 256, 16);   // 128 blocks, 16 loads/thread
        reduce_partials_kernel<<<g2, 256, 0, stream>>>(ws, out, npart, size);
    } else {
        hipMemsetAsync(out, 0, (size_t)size * sizeof(float), stream);
        int grid = (n + 255) / 256;
        if (grid > 2048) grid = 2048;
        direct_atomic_kernel<<<grid, 256, 0, stream>>>(
            index, rate, starttime, endtime, t_ptr, out, n);
    }
}